// Round 11
// baseline (73.184 us; speedup 1.0000x reference)
//
#include <hip/hip_runtime.h>
#include <math.h>

#define N_VARS 512
#define DV 4
#define EDGES 2048
#define BATCH 8192
#define CLIP_TANH 10.0f
#define ROWS 16           // batch rows per thread (r8:8=46.65, r9:16=45.05)
#define NBLK (BATCH / ROWS * N_VARS / 256)   // 1024 main blocks

typedef float f32x4 __attribute__((ext_vector_type(4)));

// ---------------------------------------------------------------------------
// Kernel P: per-column param precompute (8 blocks) + zero the done-counter.
// Column e has nonzeros only at rows g in group(e)={4v..4v+3}, g!=e.
// ---------------------------------------------------------------------------
__global__ __launch_bounds__(256) void params_kernel(
    const float* __restrict__ odd_weights,   // [E,E]
    const float* __restrict__ llr_weights,   // [N,E]
    const float* __restrict__ dropout_logit, // [E]
    const float* __restrict__ u,             // [E,E]
    const float* __restrict__ mask_oe,       // [E,E]
    const float* __restrict__ mask_skip,     // [N,E]
    f32x4* __restrict__ WZ,                  // [E]
    f32x4* __restrict__ WZT,                 // [E]
    float* __restrict__ LW,                  // [E]
    int*   __restrict__ counter)
{
    int e = blockIdx.x * 256 + threadIdx.x;   // 8*256 = 2048 = E
    if (e == 0) *counter = 0;                 // reset for this launch

    int v = e >> 2;
    int base = v << 2;

    float logit = dropout_logit[e];
    float p = 1.0f / (1.0f + expf(-logit));   // sigmoid(logit)
    float q = 1.0f / (1.0f + expf(logit));    // sigmoid(-logit)

    f32x4 wz, wzt;
#pragma unroll
    for (int j = 0; j < 4; ++j) {
        size_t off = (size_t)(base + j) * EDGES + e;
        float w = odd_weights[off] * mask_oe[off];
        float uu = u[off];
        wz[j]  = (uu < p) ? w : 0.0f;
        wzt[j] = (uu > q) ? w : 0.0f;
    }
    WZ[e]  = wz;
    WZT[e] = wzt;

    size_t soff = (size_t)v * EDGES + e;
    LW[e] = llr_weights[soff] * mask_skip[soff];
}

// tanh(m/2) = (e^m - 1)/(e^m + 1), m pre-clipped to [-10,10]; fast rcp.
__device__ __forceinline__ float tanh_half(float m) {
    float t = __expf(m);
    return (t - 1.0f) * __builtin_amdgcn_rcpf(t + 1.0f);
}

// ---------------------------------------------------------------------------
// Kernel M: fused main pass.
//  phase 1: block b computes KL row-sums for odd_weights rows 2b, 2b+1
//           (16 KB coalesced; overlaps with the MLP phase's memory slack)
//  phase 2: MLP batch pass (ROWS rows per thread, params register-resident)
//  phase 3: last block to finish (device-scope counter) reduces rowv[2048]
//           in fixed order -> bit-deterministic kl. rowv re-read via
//           atomicAdd(ptr,0) to bypass potentially-stale per-XCD caches.
// ---------------------------------------------------------------------------
__global__ __launch_bounds__(256) void main_kernel(
    const float* __restrict__ x,    // [B,E]
    const float* __restrict__ llr,  // [B,N]
    const float* __restrict__ odd_weights,   // [E,E]
    const float* __restrict__ dropout_logit, // [E]
    const f32x4* __restrict__ WZ,
    const f32x4* __restrict__ WZT,
    const float* __restrict__ LW,
    float* __restrict__ rowv,       // [E]
    int*   __restrict__ counter,
    float* __restrict__ out0,       // [B,E]
    float* __restrict__ out1,       // [B,E]
    float* __restrict__ kl)         // [1]
{
    int t = threadIdx.x;
    __shared__ float red[4];
    __shared__ int isLast;

    // ---------- phase 1: two KL row-sums per block ----------
#pragma unroll
    for (int rr = 0; rr < 2; ++rr) {
        int e = blockIdx.x * 2 + rr;
        const f32x4* row = (const f32x4*)(odd_weights + (size_t)e * EDGES);
        float s = 0.0f;
#pragma unroll
        for (int i = t; i < EDGES / 4; i += 256) {
            f32x4 w = row[i];
            s = fmaf(w.x, w.x, s);
            s = fmaf(w.y, w.y, s);
            s = fmaf(w.z, w.z, s);
            s = fmaf(w.w, w.w, s);
        }
#pragma unroll
        for (int off = 32; off > 0; off >>= 1)
            s += __shfl_down(s, off, 64);
        if ((t & 63) == 0) red[t >> 6] = s;
        __syncthreads();
        if (t == 0) {
            float ss = red[0] + red[1] + red[2] + red[3];
            float logit = dropout_logit[e];
            float p = 1.0f / (1.0f + expf(-logit));
            float H1 = -p * logf(p) - (1.0f - p) * logf(1.0f - p);
            rowv[e] = 12.5f * p * ss - H1;   // (KL_SCALE^2/2) = 12.5
        }
        __syncthreads();
    }
    // publish this block's rowv, bump done-counter (device scope)
    if (t == 0) {
        __threadfence();
        int old = atomicAdd(counter, 1);
        isLast = (old == NBLK - 1);
    }

    // ---------- phase 2: MLP main pass ----------
    int idx = blockIdx.x * 256 + t;
    int v = idx & (N_VARS - 1);
    int b0 = (idx >> 9) * ROWS;

    f32x4 wz[4], wzt[4];
    float lw[4];
#pragma unroll
    for (int c = 0; c < 4; ++c) {
        int e = (v << 2) + c;
        wz[c]  = WZ[e];
        wzt[c] = WZT[e];
        lw[c]  = LW[e];
    }

    f32x4 x4[ROWS];
    float l[ROWS];
#pragma unroll
    for (int r = 0; r < ROWS; ++r) {
        x4[r] = ((const f32x4*)(x + (size_t)(b0 + r) * EDGES))[v];
        l[r]  = llr[(size_t)(b0 + r) * N_VARS + v];
    }

#pragma unroll
    for (int r = 0; r < ROWS; ++r) {
        f32x4 o0, o1;
#pragma unroll
        for (int c = 0; c < 4; ++c) {
            float lt = l[r] * lw[c];
            float m  = fmaf(x4[r].x, wz[c].x,  fmaf(x4[r].y, wz[c].y,
                       fmaf(x4[r].z, wz[c].z,  fmaf(x4[r].w, wz[c].w,  lt))));
            float mt = fmaf(x4[r].x, wzt[c].x, fmaf(x4[r].y, wzt[c].y,
                       fmaf(x4[r].z, wzt[c].z, fmaf(x4[r].w, wzt[c].w, lt))));
            m  = fminf(fmaxf(m,  -CLIP_TANH), CLIP_TANH);
            mt = fminf(fmaxf(mt, -CLIP_TANH), CLIP_TANH);
            o0[c] = tanh_half(m);
            o1[c] = tanh_half(mt);
        }
        __builtin_nontemporal_store(o0,
            &((f32x4*)(out0 + (size_t)(b0 + r) * EDGES))[v]);
        __builtin_nontemporal_store(o1,
            &((f32x4*)(out1 + (size_t)(b0 + r) * EDGES))[v]);
    }

    // ---------- phase 3: last block reduces kl (fixed order, deterministic) --
    __syncthreads();
    if (isLast) {
        float s = 0.0f;
        for (int i = t; i < EDGES; i += 256)
            s += atomicAdd(&rowv[i], 0.0f);   // device-scope fresh read
#pragma unroll
        for (int off = 32; off > 0; off >>= 1)
            s += __shfl_down(s, off, 64);
        if ((t & 63) == 0) red[t >> 6] = s;
        __syncthreads();
        if (t == 0) kl[0] = (red[0] + red[1] + red[2] + red[3]) / (float)EDGES;
    }
}

extern "C" void kernel_launch(void* const* d_in, const int* in_sizes, int n_in,
                              void* d_out, int out_size, void* d_ws, size_t ws_size,
                              hipStream_t stream) {
    const float* x             = (const float*)d_in[0];
    const float* llr           = (const float*)d_in[1];
    const float* odd_weights   = (const float*)d_in[2];
    const float* llr_weights   = (const float*)d_in[3];
    const float* dropout_logit = (const float*)d_in[4];
    const float* u             = (const float*)d_in[5];
    const float* mask_oe       = (const float*)d_in[6];
    const float* mask_skip     = (const float*)d_in[7];

    float* out0 = (float*)d_out;
    float* out1 = out0 + (size_t)BATCH * EDGES;
    float* kl   = out0 + (size_t)2 * BATCH * EDGES;

    char* ws = (char*)d_ws;
    f32x4* WZ   = (f32x4*)(ws);               // 32 KiB
    f32x4* WZT  = (f32x4*)(ws + 32768);       // 32 KiB
    float* LW   = (float*)(ws + 65536);       // 8 KiB
    float* ROWV = (float*)(ws + 73728);       // 8 KiB
    int*   CNT  = (int*)  (ws + 81920);       // 4 B

    params_kernel<<<EDGES / 256, 256, 0, stream>>>(
        odd_weights, llr_weights, dropout_logit, u, mask_oe, mask_skip,
        WZ, WZT, LW, CNT);

    main_kernel<<<NBLK, 256, 0, stream>>>(
        x, llr, odd_weights, dropout_logit, WZ, WZT, LW, ROWV, CNT,
        out0, out1, kl);
}

// Round 12
// 71.205 us; speedup vs baseline: 1.0278x; 1.0278x over previous
//
#include <hip/hip_runtime.h>
#include <math.h>

#define N_VARS 512
#define DV 4
#define EDGES 2048
#define BATCH 8192
#define CLIP_TANH 10.0f
#define ROWS 16                 // batch rows per thread (r9: 16 -> 45.05us)
#define NBLK_MLP (BATCH / ROWS * N_VARS / 256)  // 1024 MLP blocks
#define NBLK_SCAN 64                            // KL scan blocks
#define SCAN_ROWS (EDGES / NBLK_SCAN)           // 32 rows per scan block

typedef float f32x4 __attribute__((ext_vector_type(4)));

// ---------------------------------------------------------------------------
// Kernel P: per-column param precompute (8 blocks) + reset done-counter.
// ---------------------------------------------------------------------------
__global__ __launch_bounds__(256) void params_kernel(
    const float* __restrict__ odd_weights,   // [E,E]
    const float* __restrict__ llr_weights,   // [N,E]
    const float* __restrict__ dropout_logit, // [E]
    const float* __restrict__ u,             // [E,E]
    const float* __restrict__ mask_oe,       // [E,E]
    const float* __restrict__ mask_skip,     // [N,E]
    f32x4* __restrict__ WZ,                  // [E]
    f32x4* __restrict__ WZT,                 // [E]
    float* __restrict__ LW,                  // [E]
    int*   __restrict__ counter)
{
    int e = blockIdx.x * 256 + threadIdx.x;   // 8*256 = 2048 = E
    if (e == 0) *counter = 0;

    int v = e >> 2;
    int base = v << 2;

    float logit = dropout_logit[e];
    float p = 1.0f / (1.0f + expf(-logit));   // sigmoid(logit)
    float q = 1.0f / (1.0f + expf(logit));    // sigmoid(-logit)

    f32x4 wz, wzt;
#pragma unroll
    for (int j = 0; j < 4; ++j) {
        size_t off = (size_t)(base + j) * EDGES + e;
        float w = odd_weights[off] * mask_oe[off];
        float uu = u[off];
        wz[j]  = (uu < p) ? w : 0.0f;
        wzt[j] = (uu > q) ? w : 0.0f;
    }
    WZ[e]  = wz;
    WZT[e] = wzt;

    size_t soff = (size_t)v * EDGES + e;
    LW[e] = llr_weights[soff] * mask_skip[soff];
}

// tanh(m/2) = (e^m - 1)/(e^m + 1), m pre-clipped to [-10,10]; fast rcp.
__device__ __forceinline__ float tanh_half(float m) {
    float t = __expf(m);
    return (t - 1.0f) * __builtin_amdgcn_rcpf(t + 1.0f);
}

// ---------------------------------------------------------------------------
// Kernel M: blocks [0,NBLK_MLP) = r10 MLP path, byte-identical workload.
// Blocks [NBLK_MLP, NBLK_MLP+NBLK_SCAN) = KL scan blocks (32 rows each),
// co-scheduled with the MLP blocks so the 16 MB odd_weights scan hides in
// the MLP phase's bandwidth slack. Last scan block to finish (device-scope
// counter) does the fixed-order kl reduce (bit-deterministic); rowv re-read
// via atomicAdd(ptr,0) to bypass stale per-XCD cache lines.
// ---------------------------------------------------------------------------
__global__ __launch_bounds__(256) void main_kernel(
    const float* __restrict__ x,    // [B,E]
    const float* __restrict__ llr,  // [B,N]
    const float* __restrict__ odd_weights,   // [E,E]
    const float* __restrict__ dropout_logit, // [E]
    const f32x4* __restrict__ WZ,
    const f32x4* __restrict__ WZT,
    const float* __restrict__ LW,
    float* __restrict__ rowv,       // [E]
    int*   __restrict__ counter,
    float* __restrict__ out0,       // [B,E]
    float* __restrict__ out1,       // [B,E]
    float* __restrict__ kl)         // [1]
{
    int t = threadIdx.x;

    if (blockIdx.x >= NBLK_MLP) {
        // ---------------- scan path (64 blocks) ----------------
        __shared__ float red[4];
        __shared__ int isLast;
        int sb = blockIdx.x - NBLK_MLP;
        for (int rr = 0; rr < SCAN_ROWS; ++rr) {
            int e = sb * SCAN_ROWS + rr;
            const f32x4* row = (const f32x4*)(odd_weights + (size_t)e * EDGES);
            float s = 0.0f;
#pragma unroll
            for (int i = t; i < EDGES / 4; i += 256) {
                f32x4 w = row[i];
                s = fmaf(w.x, w.x, s);
                s = fmaf(w.y, w.y, s);
                s = fmaf(w.z, w.z, s);
                s = fmaf(w.w, w.w, s);
            }
#pragma unroll
            for (int off = 32; off > 0; off >>= 1)
                s += __shfl_down(s, off, 64);
            if ((t & 63) == 0) red[t >> 6] = s;
            __syncthreads();
            if (t == 0) {
                float ss = red[0] + red[1] + red[2] + red[3];
                float logit = dropout_logit[e];
                float p = 1.0f / (1.0f + expf(-logit));
                float H1 = -p * logf(p) - (1.0f - p) * logf(1.0f - p);
                rowv[e] = 12.5f * p * ss - H1;   // (KL_SCALE^2/2) = 12.5
            }
            __syncthreads();
        }
        if (t == 0) {
            __threadfence();
            int old = atomicAdd(counter, 1);
            isLast = (old == NBLK_SCAN - 1);
        }
        __syncthreads();
        if (isLast) {
            float s = 0.0f;
            for (int i = t; i < EDGES; i += 256)
                s += atomicAdd(&rowv[i], 0.0f);   // coherent fresh read
#pragma unroll
            for (int off = 32; off > 0; off >>= 1)
                s += __shfl_down(s, off, 64);
            if ((t & 63) == 0) red[t >> 6] = s;
            __syncthreads();
            if (t == 0)
                kl[0] = (red[0] + red[1] + red[2] + red[3]) / (float)EDGES;
        }
        return;
    }

    // ---------------- MLP path (1024 blocks; r10 body) ----------------
    int idx = blockIdx.x * 256 + t;
    int v = idx & (N_VARS - 1);
    int b0 = (idx >> 9) * ROWS;

    f32x4 wz[4], wzt[4];
    float lw[4];
#pragma unroll
    for (int c = 0; c < 4; ++c) {
        int e = (v << 2) + c;
        wz[c]  = WZ[e];
        wzt[c] = WZT[e];
        lw[c]  = LW[e];
    }

    f32x4 x4[ROWS];
    float l[ROWS];
#pragma unroll
    for (int r = 0; r < ROWS; ++r) {
        x4[r] = ((const f32x4*)(x + (size_t)(b0 + r) * EDGES))[v];
        l[r]  = llr[(size_t)(b0 + r) * N_VARS + v];
    }

#pragma unroll
    for (int r = 0; r < ROWS; ++r) {
        f32x4 o0, o1;
#pragma unroll
        for (int c = 0; c < 4; ++c) {
            float lt = l[r] * lw[c];
            float m  = fmaf(x4[r].x, wz[c].x,  fmaf(x4[r].y, wz[c].y,
                       fmaf(x4[r].z, wz[c].z,  fmaf(x4[r].w, wz[c].w,  lt))));
            float mt = fmaf(x4[r].x, wzt[c].x, fmaf(x4[r].y, wzt[c].y,
                       fmaf(x4[r].z, wzt[c].z, fmaf(x4[r].w, wzt[c].w, lt))));
            m  = fminf(fmaxf(m,  -CLIP_TANH), CLIP_TANH);
            mt = fminf(fmaxf(mt, -CLIP_TANH), CLIP_TANH);
            o0[c] = tanh_half(m);
            o1[c] = tanh_half(mt);
        }
        __builtin_nontemporal_store(o0,
            &((f32x4*)(out0 + (size_t)(b0 + r) * EDGES))[v]);
        __builtin_nontemporal_store(o1,
            &((f32x4*)(out1 + (size_t)(b0 + r) * EDGES))[v]);
    }
}

extern "C" void kernel_launch(void* const* d_in, const int* in_sizes, int n_in,
                              void* d_out, int out_size, void* d_ws, size_t ws_size,
                              hipStream_t stream) {
    const float* x             = (const float*)d_in[0];
    const float* llr           = (const float*)d_in[1];
    const float* odd_weights   = (const float*)d_in[2];
    const float* llr_weights   = (const float*)d_in[3];
    const float* dropout_logit = (const float*)d_in[4];
    const float* u             = (const float*)d_in[5];
    const float* mask_oe       = (const float*)d_in[6];
    const float* mask_skip     = (const float*)d_in[7];

    float* out0 = (float*)d_out;
    float* out1 = out0 + (size_t)BATCH * EDGES;
    float* kl   = out0 + (size_t)2 * BATCH * EDGES;

    char* ws = (char*)d_ws;
    f32x4* WZ   = (f32x4*)(ws);               // 32 KiB
    f32x4* WZT  = (f32x4*)(ws + 32768);       // 32 KiB
    float* LW   = (float*)(ws + 65536);       // 8 KiB
    float* ROWV = (float*)(ws + 73728);       // 8 KiB
    int*   CNT  = (int*)  (ws + 81920);       // 4 B

    params_kernel<<<EDGES / 256, 256, 0, stream>>>(
        odd_weights, llr_weights, dropout_logit, u, mask_oe, mask_skip,
        WZ, WZT, LW, CNT);

    main_kernel<<<NBLK_MLP + NBLK_SCAN, 256, 0, stream>>>(
        x, llr, odd_weights, dropout_logit, WZ, WZT, LW, ROWV, CNT,
        out0, out1, kl);
}

// Round 13
// 67.165 us; speedup vs baseline: 1.0896x; 1.0602x over previous
//
#include <hip/hip_runtime.h>
#include <math.h>

#define N_VARS 512
#define DV 4
#define EDGES 2048
#define BATCH 8192
#define CLIP_TANH 10.0f
#define ROWS 16                 // batch rows per thread (r9: 16 -> 45.05us)
#define NBLK_MLP (BATCH / ROWS * N_VARS / 256)  // 1024 MLP blocks
#define NBLK_SCAN 64                            // KL scan blocks (first in grid)
#define SCAN_ROWS (EDGES / NBLK_SCAN)           // 32 rows per scan block

typedef float f32x4 __attribute__((ext_vector_type(4)));

// ---------------------------------------------------------------------------
// Kernel P: per-column param precompute (8 blocks) + reset done-counter.
// ---------------------------------------------------------------------------
__global__ __launch_bounds__(256) void params_kernel(
    const float* __restrict__ odd_weights,   // [E,E]
    const float* __restrict__ llr_weights,   // [N,E]
    const float* __restrict__ dropout_logit, // [E]
    const float* __restrict__ u,             // [E,E]
    const float* __restrict__ mask_oe,       // [E,E]
    const float* __restrict__ mask_skip,     // [N,E]
    f32x4* __restrict__ WZ,                  // [E]
    f32x4* __restrict__ WZT,                 // [E]
    float* __restrict__ LW,                  // [E]
    int*   __restrict__ counter)
{
    int e = blockIdx.x * 256 + threadIdx.x;   // 8*256 = 2048 = E
    if (e == 0) *counter = 0;

    int v = e >> 2;
    int base = v << 2;

    float logit = dropout_logit[e];
    float p = 1.0f / (1.0f + expf(-logit));   // sigmoid(logit)
    float q = 1.0f / (1.0f + expf(logit));    // sigmoid(-logit)

    f32x4 wz, wzt;
#pragma unroll
    for (int j = 0; j < 4; ++j) {
        size_t off = (size_t)(base + j) * EDGES + e;
        float w = odd_weights[off] * mask_oe[off];
        float uu = u[off];
        wz[j]  = (uu < p) ? w : 0.0f;
        wzt[j] = (uu > q) ? w : 0.0f;
    }
    WZ[e]  = wz;
    WZT[e] = wzt;

    size_t soff = (size_t)v * EDGES + e;
    LW[e] = llr_weights[soff] * mask_skip[soff];
}

// tanh(m/2) = (e^m - 1)/(e^m + 1), m pre-clipped to [-10,10]; fast rcp.
__device__ __forceinline__ float tanh_half(float m) {
    float t = __expf(m);
    return (t - 1.0f) * __builtin_amdgcn_rcpf(t + 1.0f);
}

// ---------------------------------------------------------------------------
// Kernel M: blocks [0,NBLK_SCAN) = KL scan (32 rows each, co-scheduled from
// dispatch start); blocks [NBLK_SCAN, ...) = r10 MLP path.
// Guards against the r11/r12 codegen failure (compiler sank the batched
// loads, VGPR 36-40, 2.4x regression):
//   - __launch_bounds__(256, 1): loosest occupancy constraint for regalloc
//   - sched_barrier(0) after the load loop: loads cannot sink past it
// ---------------------------------------------------------------------------
__global__ __launch_bounds__(256, 1) void main_kernel(
    const float* __restrict__ x,    // [B,E]
    const float* __restrict__ llr,  // [B,N]
    const float* __restrict__ odd_weights,   // [E,E]
    const float* __restrict__ dropout_logit, // [E]
    const f32x4* __restrict__ WZ,
    const f32x4* __restrict__ WZT,
    const float* __restrict__ LW,
    float* __restrict__ rowv,       // [E]
    int*   __restrict__ counter,
    float* __restrict__ out0,       // [B,E]
    float* __restrict__ out1,       // [B,E]
    float* __restrict__ kl)         // [1]
{
    int t = threadIdx.x;

    if (blockIdx.x < NBLK_SCAN) {
        // ---------------- scan path (64 blocks) ----------------
        __shared__ float red[4];
        __shared__ int isLast;
        int sb = blockIdx.x;
        for (int rr = 0; rr < SCAN_ROWS; ++rr) {
            int e = sb * SCAN_ROWS + rr;
            const f32x4* row = (const f32x4*)(odd_weights + (size_t)e * EDGES);
            float s = 0.0f;
#pragma unroll
            for (int i = t; i < EDGES / 4; i += 256) {
                f32x4 w = row[i];
                s = fmaf(w.x, w.x, s);
                s = fmaf(w.y, w.y, s);
                s = fmaf(w.z, w.z, s);
                s = fmaf(w.w, w.w, s);
            }
#pragma unroll
            for (int off = 32; off > 0; off >>= 1)
                s += __shfl_down(s, off, 64);
            if ((t & 63) == 0) red[t >> 6] = s;
            __syncthreads();
            if (t == 0) {
                float ss = red[0] + red[1] + red[2] + red[3];
                float logit = dropout_logit[e];
                float p = 1.0f / (1.0f + expf(-logit));
                float H1 = -p * logf(p) - (1.0f - p) * logf(1.0f - p);
                rowv[e] = 12.5f * p * ss - H1;   // (KL_SCALE^2/2) = 12.5
            }
            __syncthreads();
        }
        if (t == 0) {
            __threadfence();                      // release rowv
            int old = atomicAdd(counter, 1);
            isLast = (old == NBLK_SCAN - 1);
        }
        __syncthreads();
        if (isLast) {
            __threadfence();                      // acquire side
            float s = 0.0f;
            for (int i = t; i < EDGES; i += 256)
                s += atomicAdd(&rowv[i], 0.0f);   // coherent fresh read
#pragma unroll
            for (int off = 32; off > 0; off >>= 1)
                s += __shfl_down(s, off, 64);
            if ((t & 63) == 0) red[t >> 6] = s;
            __syncthreads();
            if (t == 0)
                kl[0] = (red[0] + red[1] + red[2] + red[3]) / (float)EDGES;
        }
        return;
    }

    // ---------------- MLP path (1024 blocks; r10 body) ----------------
    int idx = (blockIdx.x - NBLK_SCAN) * 256 + t;
    int v = idx & (N_VARS - 1);
    int b0 = (idx >> 9) * ROWS;

    f32x4 wz[4], wzt[4];
    float lw[4];
#pragma unroll
    for (int c = 0; c < 4; ++c) {
        int e = (v << 2) + c;
        wz[c]  = WZ[e];
        wzt[c] = WZT[e];
        lw[c]  = LW[e];
    }

    f32x4 x4[ROWS];
    float l[ROWS];
#pragma unroll
    for (int r = 0; r < ROWS; ++r) {
        x4[r] = ((const f32x4*)(x + (size_t)(b0 + r) * EDGES))[v];
        l[r]  = llr[(size_t)(b0 + r) * N_VARS + v];
    }
    // Pin the 16-deep load window: nothing above may sink below this point.
    __builtin_amdgcn_sched_barrier(0);

#pragma unroll
    for (int r = 0; r < ROWS; ++r) {
        f32x4 o0, o1;
#pragma unroll
        for (int c = 0; c < 4; ++c) {
            float lt = l[r] * lw[c];
            float m  = fmaf(x4[r].x, wz[c].x,  fmaf(x4[r].y, wz[c].y,
                       fmaf(x4[r].z, wz[c].z,  fmaf(x4[r].w, wz[c].w,  lt))));
            float mt = fmaf(x4[r].x, wzt[c].x, fmaf(x4[r].y, wzt[c].y,
                       fmaf(x4[r].z, wzt[c].z, fmaf(x4[r].w, wzt[c].w, lt))));
            m  = fminf(fmaxf(m,  -CLIP_TANH), CLIP_TANH);
            mt = fminf(fmaxf(mt, -CLIP_TANH), CLIP_TANH);
            o0[c] = tanh_half(m);
            o1[c] = tanh_half(mt);
        }
        __builtin_nontemporal_store(o0,
            &((f32x4*)(out0 + (size_t)(b0 + r) * EDGES))[v]);
        __builtin_nontemporal_store(o1,
            &((f32x4*)(out1 + (size_t)(b0 + r) * EDGES))[v]);
    }
}

extern "C" void kernel_launch(void* const* d_in, const int* in_sizes, int n_in,
                              void* d_out, int out_size, void* d_ws, size_t ws_size,
                              hipStream_t stream) {
    const float* x             = (const float*)d_in[0];
    const float* llr           = (const float*)d_in[1];
    const float* odd_weights   = (const float*)d_in[2];
    const float* llr_weights   = (const float*)d_in[3];
    const float* dropout_logit = (const float*)d_in[4];
    const float* u             = (const float*)d_in[5];
    const float* mask_oe       = (const float*)d_in[6];
    const float* mask_skip     = (const float*)d_in[7];

    float* out0 = (float*)d_out;
    float* out1 = out0 + (size_t)BATCH * EDGES;
    float* kl   = out0 + (size_t)2 * BATCH * EDGES;

    char* ws = (char*)d_ws;
    f32x4* WZ   = (f32x4*)(ws);               // 32 KiB
    f32x4* WZT  = (f32x4*)(ws + 32768);       // 32 KiB
    float* LW   = (float*)(ws + 65536);       // 8 KiB
    float* ROWV = (float*)(ws + 73728);       // 8 KiB
    int*   CNT  = (int*)  (ws + 81920);       // 4 B

    params_kernel<<<EDGES / 256, 256, 0, stream>>>(
        odd_weights, llr_weights, dropout_logit, u, mask_oe, mask_skip,
        WZ, WZT, LW, CNT);

    main_kernel<<<NBLK_SCAN + NBLK_MLP, 256, 0, stream>>>(
        x, llr, odd_weights, dropout_logit, WZ, WZT, LW, ROWV, CNT,
        out0, out1, kl);
}

// Round 14
// 44.020 us; speedup vs baseline: 1.6625x; 1.5258x over previous
//
#include <hip/hip_runtime.h>
#include <math.h>

#define N_VARS 512
#define DV 4
#define EDGES 2048
#define BATCH 8192
#define CLIP_TANH 10.0f
#define ROWS 16  // batch rows per thread (r8: ROWS=8 46.65us, r9: ROWS=16 45.05us)

typedef float f32x4 __attribute__((ext_vector_type(4)));

// ---------------------------------------------------------------------------
// Kernel A (fused): blocks [0,2048) do the per-row ||odd_weights||^2 KL rows;
// blocks [2048,2056) do the per-column parameter precompute.
// Plain cached loads — inputs get L3 reuse across replays (NT loads regressed,
// r7: 57.0 vs 53.5 µs). Heterogeneous-path fusion into main_kernel regressed
// r11/r12/r13 (compiler sank the MLP load batch; VGPR 36-84, 67-73 µs) — keep
// the scan in THIS kernel, where both paths are small.
// ---------------------------------------------------------------------------
__global__ __launch_bounds__(256) void prep_kernel(
    const float* __restrict__ odd_weights,   // [E,E]
    const float* __restrict__ llr_weights,   // [N,E]
    const float* __restrict__ dropout_logit, // [E]
    const float* __restrict__ u,             // [E,E]
    const float* __restrict__ mask_oe,       // [E,E]
    const float* __restrict__ mask_skip,     // [N,E]
    f32x4* __restrict__ WZ,                  // [E]
    f32x4* __restrict__ WZT,                 // [E]
    float* __restrict__ LW,                  // [E]
    float* __restrict__ rowv)                // [E]
{
    int blk = blockIdx.x;
    int t = threadIdx.x;

    if (blk < EDGES) {
        // ---- KL row-sum: sum_j odd_weights[blk][j]^2 ----
        int e = blk;
        const f32x4* row = (const f32x4*)(odd_weights + (size_t)e * EDGES);
        float s = 0.0f;
#pragma unroll
        for (int i = t; i < EDGES / 4; i += 256) {
            f32x4 w = row[i];
            s = fmaf(w.x, w.x, s);
            s = fmaf(w.y, w.y, s);
            s = fmaf(w.z, w.z, s);
            s = fmaf(w.w, w.w, s);
        }
#pragma unroll
        for (int off = 32; off > 0; off >>= 1)
            s += __shfl_down(s, off, 64);
        __shared__ float red[4];
        if ((t & 63) == 0) red[t >> 6] = s;
        __syncthreads();
        if (t == 0) {
            float ss = red[0] + red[1] + red[2] + red[3];
            float logit = dropout_logit[e];
            float p = 1.0f / (1.0f + expf(-logit));
            float H1 = -p * logf(p) - (1.0f - p) * logf(1.0f - p);
            rowv[e] = 12.5f * p * ss - H1;   // (KL_SCALE^2/2) = 12.5
        }
    } else {
        // ---- per-column param precompute (tiny scatter) ----
        int e = (blk - EDGES) * 256 + t;
        int v = e >> 2;
        int base = v << 2;

        float logit = dropout_logit[e];
        float p = 1.0f / (1.0f + expf(-logit));   // sigmoid(logit)
        float q = 1.0f / (1.0f + expf(logit));    // sigmoid(-logit)

        f32x4 wz, wzt;
#pragma unroll
        for (int j = 0; j < 4; ++j) {
            size_t off = (size_t)(base + j) * EDGES + e;
            float w = odd_weights[off] * mask_oe[off];
            float uu = u[off];
            wz[j]  = (uu < p) ? w : 0.0f;
            wzt[j] = (uu > q) ? w : 0.0f;
        }
        WZ[e]  = wz;
        WZT[e] = wzt;

        size_t soff = (size_t)v * EDGES + e;
        LW[e] = llr_weights[soff] * mask_skip[soff];
    }
}

// tanh(m/2) = (e^m - 1)/(e^m + 1), m pre-clipped to [-10,10]; fast rcp.
__device__ __forceinline__ float tanh_half(float m) {
    float t = __expf(m);
    return (t - 1.0f) * __builtin_amdgcn_rcpf(t + 1.0f);
}

// ---------------------------------------------------------------------------
// Kernel B: main pass. One thread per (variable group v, chunk of ROWS rows).
// Params register-resident; ROWS independent x-loads issued up front (MLP).
// Output stores NONTEMPORAL (outputs never re-read in the timed loop); input
// loads cached (L3 reuse). Block 0 additionally performs the final KL mean.
// ---------------------------------------------------------------------------
__global__ __launch_bounds__(256) void main_kernel(
    const float* __restrict__ x,    // [B,E]
    const float* __restrict__ llr,  // [B,N]
    const f32x4* __restrict__ WZ,
    const f32x4* __restrict__ WZT,
    const float* __restrict__ LW,
    const float* __restrict__ rowv, // [E]
    float* __restrict__ out0,       // [B,E]
    float* __restrict__ out1,       // [B,E]
    float* __restrict__ kl)         // [1]
{
    int idx = blockIdx.x * 256 + threadIdx.x;   // (B/ROWS)*N_VARS threads
    int v = idx & (N_VARS - 1);
    int b0 = (idx >> 9) * ROWS;

    // register-resident params for this variable group's 4 output columns
    f32x4 wz[4], wzt[4];
    float lw[4];
#pragma unroll
    for (int c = 0; c < 4; ++c) {
        int e = (v << 2) + c;
        wz[c]  = WZ[e];
        wzt[c] = WZT[e];
        lw[c]  = LW[e];
    }

    // issue all x / llr loads up front (independent -> overlapped)
    f32x4 x4[ROWS];
    float l[ROWS];
#pragma unroll
    for (int r = 0; r < ROWS; ++r) {
        x4[r] = ((const f32x4*)(x + (size_t)(b0 + r) * EDGES))[v];
        l[r]  = llr[(size_t)(b0 + r) * N_VARS + v];
    }

#pragma unroll
    for (int r = 0; r < ROWS; ++r) {
        f32x4 o0, o1;
#pragma unroll
        for (int c = 0; c < 4; ++c) {
            float lt = l[r] * lw[c];
            float m  = fmaf(x4[r].x, wz[c].x,  fmaf(x4[r].y, wz[c].y,
                       fmaf(x4[r].z, wz[c].z,  fmaf(x4[r].w, wz[c].w,  lt))));
            float mt = fmaf(x4[r].x, wzt[c].x, fmaf(x4[r].y, wzt[c].y,
                       fmaf(x4[r].z, wzt[c].z, fmaf(x4[r].w, wzt[c].w, lt))));
            m  = fminf(fmaxf(m,  -CLIP_TANH), CLIP_TANH);
            mt = fminf(fmaxf(mt, -CLIP_TANH), CLIP_TANH);
            o0[c] = tanh_half(m);
            o1[c] = tanh_half(mt);
        }
        __builtin_nontemporal_store(o0,
            &((f32x4*)(out0 + (size_t)(b0 + r) * EDGES))[v]);
        __builtin_nontemporal_store(o1,
            &((f32x4*)(out1 + (size_t)(b0 + r) * EDGES))[v]);
    }

    // ---- final KL mean in block 0 (deterministic tree reduce) ----
    if (blockIdx.x == 0) {
        int t = threadIdx.x;
        float s = 0.0f;
#pragma unroll
        for (int i = t; i < EDGES; i += 256) s += rowv[i];
#pragma unroll
        for (int off = 32; off > 0; off >>= 1)
            s += __shfl_down(s, off, 64);
        __shared__ float red[4];
        if ((t & 63) == 0) red[t >> 6] = s;
        __syncthreads();
        if (t == 0) kl[0] = (red[0] + red[1] + red[2] + red[3]) / (float)EDGES;
    }
}

extern "C" void kernel_launch(void* const* d_in, const int* in_sizes, int n_in,
                              void* d_out, int out_size, void* d_ws, size_t ws_size,
                              hipStream_t stream) {
    const float* x             = (const float*)d_in[0];
    const float* llr           = (const float*)d_in[1];
    const float* odd_weights   = (const float*)d_in[2];
    const float* llr_weights   = (const float*)d_in[3];
    const float* dropout_logit = (const float*)d_in[4];
    const float* u             = (const float*)d_in[5];
    const float* mask_oe       = (const float*)d_in[6];
    const float* mask_skip     = (const float*)d_in[7];

    float* out0 = (float*)d_out;
    float* out1 = out0 + (size_t)BATCH * EDGES;
    float* kl   = out0 + (size_t)2 * BATCH * EDGES;

    char* ws = (char*)d_ws;
    f32x4* WZ  = (f32x4*)(ws);                // 32 KiB
    f32x4* WZT = (f32x4*)(ws + 32768);        // 32 KiB
    float* LW  = (float*)(ws + 65536);        // 8 KiB
    float* ROWV= (float*)(ws + 73728);        // 8 KiB

    prep_kernel<<<EDGES + EDGES / 256, 256, 0, stream>>>(
        odd_weights, llr_weights, dropout_logit, u, mask_oe, mask_skip,
        WZ, WZT, LW, ROWV);

    int threads = (BATCH / ROWS) * N_VARS;    // 262144
    main_kernel<<<threads / 256, 256, 0, stream>>>(
        x, llr, WZ, WZT, LW, ROWV, out0, out1, kl);
}